// Round 7
// baseline (282.252 us; speedup 1.0000x reference)
//
#include <hip/hip_runtime.h>

#define T_LEN 2048
#define B_SZ  2048
#define H_SZ  8
#define WARM  12      // layer l live from tick 3l; outputs from tick 12
#define XS_N  2064

#if __has_builtin(__builtin_amdgcn_exp2f)
  #define EXP2F(x) __builtin_amdgcn_exp2f(x)
#else
  #define EXP2F(x) __expf(0.69314718055994531f * (x))
#endif

// row_ror:(CTRL-0x120) within 16-lane rows; 8-periodic data -> rotate mod 8.
// Single-use results are foldable into the consuming VOP1/VOP2 (DPP-combine).
template<int CTRL>
__device__ __forceinline__ float rot_dpp(float v) {
    return __int_as_float(
        __builtin_amdgcn_update_dpp(0, __float_as_int(v), CTRL, 0xF, 0xF, false));
}

__global__ __launch_bounds__(64, 1)
void rnn_expsplit(const float* __restrict__ x,
                  const float* __restrict__ h0_in,
                  const float* __restrict__ w_ih0,
                  const float* __restrict__ w_ih,
                  const float* __restrict__ w_hh,
                  const float* __restrict__ b_ih,
                  const float* __restrict__ b_hh,
                  const float* __restrict__ w_lin,
                  const float* __restrict__ b_lin,
                  float* __restrict__ out)
{
    __shared__ __align__(16) float xs[XS_N];

    const int lane = threadIdx.x;
    const int u    = lane & 7;          // hidden unit (rows hold units 0-7 twice)
    const int l    = lane >> 4;         // row = layer
    const int lp   = (l + 3) & 3;       // import source row (row0 <- row3 = output)
    const int bidx = ((lp << 4) | (lane & 15)) << 2;   // any copy in source row

    for (int i = lane; i < XS_N; i += 64) xs[i] = 0.0f;
    __syncthreads();
    for (int i = lane; i < T_LEN; i += 64) xs[i] = x[(size_t)i * B_SZ + (B_SZ - 1)];
    __syncthreads();

    // DPP direction probe (HW-verified round 3)
    int rot1 = __builtin_amdgcn_update_dpp(0, lane, 0x121, 0xF, 0xF, false);
    const bool plus = ((rot1 & 15) == ((lane + 1) & 15));

    const float C   = 2.0f * 1.4426950408889634f;  // h=tanh(a) -> r=rcp(exp2(C*a)+1)
    const float m2C = -2.0f * C;

    float whh_rs = 0.0f, wih_rs = 0.0f, wlin_rs = 0.0f;
    #pragma unroll
    for (int j = 0; j < 8; ++j) {
        whh_rs += w_hh[(l * H_SZ + u) * H_SZ + j];
        if (l > 0) wih_rs += w_ih[((l - 1) * H_SZ + u) * H_SZ + j];
        wlin_rs += w_lin[j];
    }
    const float bl_tot = wlin_rs + b_lin[0];

    // own-dot weights (all lanes) and export weights (w_ih[l] scaled, or w_lin for row3)
    float wown[8], wexp[8];
    #pragma unroll
    for (int s = 0; s < 8; ++s) {
        int j = plus ? ((u + s) & 7) : ((u - s) & 7);
        wown[s] = m2C * w_hh[(l * H_SZ + u) * H_SZ + j];
        wexp[s] = (l < 3) ? m2C * w_ih[(l * H_SZ + u) * H_SZ + j] : -2.0f * w_lin[j];
    }
    const float tbase  = (l == 3) ? bl_tot : 0.0f;   // output bias rides row3's export
    const float xconst = C * (b_ih[l * H_SZ + u] + b_hh[l * H_SZ + u]
                              + whh_rs + ((l > 0) ? wih_rs : 0.0f));
    const float wx2 = (l == 0) ? C * w_ih0[u] : 0.0f;
    const float sel = (l == 0) ? 0.0f : 1.0f;   // row0's import is the OUTPUT

    // state r = (1 - h)/2
    float r = __builtin_fmaf(-0.5f, h0_in[((size_t)l * B_SZ + (B_SZ - 1)) * H_SZ + u], 0.5f);
    float ipA = 0.0f, ipB = 0.0f;     // bpermute issued at tick k -> consumed k+2
    // E_pre primed for ticks 0,1 (imports are zero-init)
    float epA = EXP2F(__builtin_fmaf(wx2, xs[0], xconst));
    float epB = EXP2F(__builtin_fmaf(wx2, xs[1], xconst));

    // tick k: critical cycle r -> pair-dots -> exp2 x4 -> prod -> xE_pre -> +1 -> rcp
    auto tick = [&](float ep_cur, float& ip_slot, float& outv) -> float {
        float p0 = __builtin_fmaf(wown[1], rot_dpp<0x121>(r), wown[0] * r);
        float p1 = __builtin_fmaf(wown[3], rot_dpp<0x123>(r), wown[2] * rot_dpp<0x122>(r));
        float p2 = __builtin_fmaf(wown[5], rot_dpp<0x125>(r), wown[4] * rot_dpp<0x124>(r));
        float p3 = __builtin_fmaf(wown[7], rot_dpp<0x127>(r), wown[6] * rot_dpp<0x126>(r));
        float e0 = EXP2F(p0), e1 = EXP2F(p1), e2 = EXP2F(p2), e3 = EXP2F(p3);
        float q  = (e0 * e1) * (e2 * e3);
        float et = q * ep_cur;
        float rn = __builtin_amdgcn_rcpf(et + 1.0f);
        // export dot (2-tick slack; serial chain fills stall slots)
        float E = __builtin_fmaf(wexp[0], r, tbase);
        E = __builtin_fmaf(wexp[1], rot_dpp<0x121>(r), E);
        E = __builtin_fmaf(wexp[2], rot_dpp<0x122>(r), E);
        E = __builtin_fmaf(wexp[3], rot_dpp<0x123>(r), E);
        E = __builtin_fmaf(wexp[4], rot_dpp<0x124>(r), E);
        E = __builtin_fmaf(wexp[5], rot_dpp<0x125>(r), E);
        E = __builtin_fmaf(wexp[6], rot_dpp<0x126>(r), E);
        E = __builtin_fmaf(wexp[7], rot_dpp<0x127>(r), E);
        outv = ip_slot;                          // row0: out[k-12] (bias folded)
        ip_slot = __int_as_float(__builtin_amdgcn_ds_bpermute(bidx, __float_as_int(E)));
        return rn;
    };
    // E_pre for tick k+1, from import issued at k-1 (slot (k+1)&1, landed)
    auto mk_ep = [&](float ip_lag, float xnext) -> float {
        return EXP2F(__builtin_fmaf(sel, ip_lag,
                     __builtin_fmaf(wx2, xnext, xconst)));
    };

    // ---- warm-up ticks 0..11: layer l's r updates only from tick 3l ----
    #pragma unroll
    for (int k = 0; k < WARM; ++k) {
        float dummy, rn;
        if (k & 1) { rn = tick(epB, ipB, dummy); epA = mk_ep(ipA, xs[k + 1]); }
        else       { rn = tick(epA, ipA, dummy); epB = mk_ep(ipB, xs[k + 1]); }
        r = (k >= 3 * l) ? rn : r;
    }

    // ---- main: ticks 12..2059; tick k emits out[k-12]; xq prefetched 1 block ----
    const float4* xsv = (const float4*)xs;
    float4 xq = xsv[3];                       // xs[12..15]
    for (int kb = WARM; kb <= 2056; kb += 4) {
        float4 xnxt = xsv[(kb >> 2) + 1];     // prefetch xs[kb+4..kb+7]
        float ov0, ov1, ov2, ov3;
        r = tick(epA, ipA, ov0); epB = mk_ep(ipB, xq.y);
        r = tick(epB, ipB, ov1); epA = mk_ep(ipA, xq.z);
        r = tick(epA, ipA, ov2); epB = mk_ep(ipB, xq.w);
        r = tick(epB, ipB, ov3); epA = mk_ep(ipA, xnxt.x);
        if (lane == 0)
            *(float4*)(out + (kb - WARM)) = make_float4(ov0, ov1, ov2, ov3);
        xq = xnxt;
    }
}

extern "C" void kernel_launch(void* const* d_in, const int* in_sizes, int n_in,
                              void* d_out, int out_size, void* d_ws, size_t ws_size,
                              hipStream_t stream) {
    const float* x     = (const float*)d_in[0];
    const float* h0    = (const float*)d_in[1];
    const float* w_ih0 = (const float*)d_in[2];
    const float* w_ih  = (const float*)d_in[3];
    const float* w_hh  = (const float*)d_in[4];
    const float* b_ih  = (const float*)d_in[5];
    const float* b_hh  = (const float*)d_in[6];
    const float* w_lin = (const float*)d_in[7];
    const float* b_lin = (const float*)d_in[8];
    float* out = (float*)d_out;

    rnn_expsplit<<<dim3(1), dim3(64), 0, stream>>>(
        x, h0, w_ih0, w_ih, w_hh, b_ih, b_hh, w_lin, b_lin, out);
}